// Round 9
// baseline (266.076 us; speedup 1.0000x reference)
//
#include <hip/hip_runtime.h>

// Problem constants (fixed by setup_inputs)
#define B_   4
#define C_   256
#define H_   96
#define W_   128
#define F_   9
#define G_   4
#define CG   64            // channels per group
#define NC4  16            // channel QUADS per group
#define NO   81            // offsets
#define HW_  (H_ * W_)

// One dy per pass; block = 8 output rows x 128 cols; 4 same-parity px/thread
#define TROWS 8
#define TCOLS 144                 // 128 + 16 halo cols
#define PCOLS 72                  // col2 per parity (= pairs per row)
#define PSTR  74                  // padded parity-plane stride in 8B entries (592 B)
#define PTE   (TROWS * 2 * PSTR)  // 1184 entries per buffer
#define NPAIR (TROWS * PCOLS)     // 576 pair units to stage
#define NCH   3                   // 256 + 256 + 64

typedef _Float16 half2v __attribute__((ext_vector_type(2)));
typedef unsigned u32x2 __attribute__((ext_vector_type(2)));
typedef unsigned u32x4 __attribute__((ext_vector_type(4)));
typedef float    f32x2 __attribute__((ext_vector_type(2)));

__device__ __forceinline__ half2v u2h(unsigned u) {
    half2v h; __builtin_memcpy(&h, &u, 4); return h;
}
__device__ __forceinline__ unsigned h2u(half2v h) {
    unsigned u; __builtin_memcpy(&u, &h, 4); return u;
}
__device__ __forceinline__ half2v pkrtz(float a, float b) {
    auto r = __builtin_amdgcn_cvt_pkrtz(a, b);
    half2v h; __builtin_memcpy(&h, &r, 4); return h;
}
__device__ __forceinline__ unsigned pkrtz_u(float a, float b) {
    auto r = __builtin_amdgcn_cvt_pkrtz(a, b);
    unsigned u; __builtin_memcpy(&u, &r, 4); return u;
}

#if __has_builtin(__builtin_amdgcn_fdot2)
#define FDOT2(a, b, c) __builtin_amdgcn_fdot2((a), (b), (c), false)
#else
__device__ __forceinline__ float fdot2_fb(half2v a, half2v b, float c) {
    return c + (float)a[0] * (float)b[0] + (float)a[1] * (float)b[1];
}
#define FDOT2(a, b, c) fdot2_fb((a), (b), (c))
#endif

// Pack weights [C,9,9] f32 -> [g][c4][o] as 4-channel (2x f16x2) in d_ws
__global__ void pack_weights_kernel(const float* __restrict__ w,
                                    u32x2* __restrict__ wp) {
    int i = blockIdx.x * blockDim.x + threadIdx.x;
    if (i >= G_ * NC4 * NO) return;
    int o  = i % NO;
    int c4 = (i / NO) % NC4;
    int g  = i / (NO * NC4);
    const float* base = w + (size_t)(g * CG + 4 * c4) * NO + o;
    u32x2 r;
    r.x = pkrtz_u(base[0], base[NO]);
    r.y = pkrtz_u(base[2 * NO], base[3 * NO]);
    wp[i] = r;
}

template <bool PACKED>
__global__ __launch_bounds__(256)
void wcorr_kernel(const float* __restrict__ in1, const float* __restrict__ in2,
                  const u32x2* __restrict__ wp, const float* __restrict__ wraw,
                  float* __restrict__ out) {
    // layout: entry = (row*2 + parity)*PSTR + col2   (8B entries, 74-padded)
    __shared__ u32x2 tile[2][PTE];   // 18,944 B

    // grid = 8 XCD x 24 tuples x 9 dy = 1728.  Round-robin dispatch puts
    // bid&7 on XCD (bid&7); dy is innermost per tuple so the 9 blocks that
    // share in1 rows run consecutively on the SAME XCD -> L2 filters re-reads.
    int bid  = blockIdx.x;
    int xcd  = bid & 7;
    int slot = bid >> 3;           // 0..215
    int tIdx = slot / 9;           // 0..23
    int dy   = slot - tIdx * 9;    // 0..8
    int T    = tIdx * 8 + xcd;     // 0..191
    int pair = T & 15;             // b*4+g
    int hblk = T >> 4;             // 0..11
    int b = pair >> 2, g = pair & 3;
    int h0 = hblk * TROWS;

    int t = threadIdx.x;
    int row_t = t >> 5;            // 0..7 output row within tile
    int i = t & 31;
    int p = i >> 4;                // parity
    int j = i & 15;                // px-block: cols j*8+p + {0,2,4,6}
    const int c0 = j * 8 + p;

    const float* in1g = in1 + (size_t)(b * C_ + g * CG) * HW_;
    const float* in2g = in2 + (size_t)(b * C_ + g * CG) * HW_;

    // ---- staging geometry (c4-invariant): pair units, clamp + per-px mask ----
    const int gr0 = h0 + 2 * dy - 8;
    int po[NCH]; unsigned mk0[NCH], mk1[NCH]; int li0[NCH];
#pragma unroll
    for (int c = 0; c < NCH; ++c) {
        int pidx = c * 256 + t;
        int row  = pidx / PCOLS;
        int pcol = pidx - row * PCOLS;
        int gr = gr0 + row;
        int gc = 2 * pcol - 8;
        bool grv = gr >= 0 && gr < H_;
        float f0 = (grv && gc >= 0 && gc < W_) ? 1.f : 0.f;
        float f1 = (grv && gc + 1 >= 0 && gc + 1 < W_) ? 1.f : 0.f;
        int off = gr * W_ + gc;
        off = off < 0 ? 0 : (off > HW_ - 2 ? HW_ - 2 : off);
        po[c]  = off;
        mk0[c] = pkrtz_u(f0, f0);
        mk1[c] = pkrtz_u(f1, f1);
        li0[c] = row * (2 * PSTR) + pcol;    // parity-0 entry; parity-1 = +PSTR
    }

    float acc[4][F_];
#pragma unroll
    for (int q = 0; q < 4; ++q)
#pragma unroll
        for (int dx = 0; dx < F_; ++dx) acc[q][dx] = 0.f;

    // ---- prologue: stage c4=0 ----
#pragma unroll
    for (int c = 0; c < NCH; ++c) {
        if (c < 2 || t < NPAIR - 512) {
            const float* q0 = in2g + po[c];
            f32x2 s0 = *(const f32x2*)(q0);
            f32x2 s1 = *(const f32x2*)(q0 + HW_);
            f32x2 s2 = *(const f32x2*)(q0 + 2 * HW_);
            f32x2 s3 = *(const f32x2*)(q0 + 3 * HW_);
            half2v m0 = u2h(mk0[c]), m1 = u2h(mk1[c]);
            u32x2 e0, e1;
            e0.x = h2u(u2h(pkrtz_u(s0.x, s1.x)) * m0);
            e0.y = h2u(u2h(pkrtz_u(s2.x, s3.x)) * m0);
            e1.x = h2u(u2h(pkrtz_u(s0.y, s1.y)) * m1);
            e1.y = h2u(u2h(pkrtz_u(s2.y, s3.y)) * m1);
            tile[0][li0[c]]        = e0;
            tile[0][li0[c] + PSTR] = e1;
        }
    }

    const int in1off = (h0 + row_t) * W_ + c0;
    const int pb = (row_t * 2 + p) * PSTR + j * 4;   // window base entry (even)

    for (int c4 = 0; c4 < NC4; ++c4) {
        const bool more = (c4 + 1 < NC4);

        // in1 for THIS c4 (latency hides under stage+barrier)
        const float* ib = in1g + (size_t)(4 * c4) * HW_ + in1off;
        float A0[4], A1[4], A2[4], A3[4];
#pragma unroll
        for (int q = 0; q < 4; ++q) {
            A0[q] = ib[2 * q];
            A1[q] = ib[HW_ + 2 * q];
            A2[q] = ib[2 * HW_ + 2 * q];
            A3[q] = ib[3 * HW_ + 2 * q];
        }

        // next tile's staged loads issued BEFORE the barrier
        f32x2 sv[NCH][4];
        if (more) {
            const float* chb = in2g + (size_t)(4 * (c4 + 1)) * HW_;
#pragma unroll
            for (int c = 0; c < NCH; ++c) {
                if (c < 2 || t < NPAIR - 512) {
                    const float* q0 = chb + po[c];
                    sv[c][0] = *(const f32x2*)(q0);
                    sv[c][1] = *(const f32x2*)(q0 + HW_);
                    sv[c][2] = *(const f32x2*)(q0 + 2 * HW_);
                    sv[c][3] = *(const f32x2*)(q0 + 3 * HW_);
                }
            }
        }

        __syncthreads();   // tile[c4&1] ready; readers done with other buffer

        if (more) {
            u32x2* dst = tile[(c4 + 1) & 1];
#pragma unroll
            for (int c = 0; c < NCH; ++c) {
                if (c < 2 || t < NPAIR - 512) {
                    half2v m0 = u2h(mk0[c]), m1 = u2h(mk1[c]);
                    u32x2 e0, e1;
                    e0.x = h2u(u2h(pkrtz_u(sv[c][0].x, sv[c][1].x)) * m0);
                    e0.y = h2u(u2h(pkrtz_u(sv[c][2].x, sv[c][3].x)) * m0);
                    e1.x = h2u(u2h(pkrtz_u(sv[c][0].y, sv[c][1].y)) * m1);
                    e1.y = h2u(u2h(pkrtz_u(sv[c][2].y, sv[c][3].y)) * m1);
                    dst[li0[c]]        = e0;
                    dst[li0[c] + PSTR] = e1;
                }
            }
        }

        // pack in1 (4 px)
        half2v ha[4], hb[4];
#pragma unroll
        for (int q = 0; q < 4; ++q) {
            ha[q] = pkrtz(A0[q], A1[q]);
            hb[q] = pkrtz(A2[q], A3[q]);
        }

        // tap window: 12 entries = 6x ds_read_b128 (16B-aligned, 592B plane
        // stride -> uniform 8 lanes/bank-quad = conflict-free throughput)
        const u32x2* lt = tile[c4 & 1];
        const u32x4* tb = (const u32x4*)&lt[pb];
        u32x4 E[6];
#pragma unroll
        for (int n = 0; n < 6; ++n) E[n] = tb[n];

        const u32x2* wrow = PACKED ? (wp + ((size_t)g * NC4 + c4) * NO + dy * F_) : nullptr;
        const float* wr = wraw + (size_t)(g * CG + 4 * c4) * NO + dy * F_;

#pragma unroll
        for (int dx = 0; dx < F_; ++dx) {
            half2v wa, wb;
            if (PACKED) {
                u32x2 wv = wrow[dx];            // block-uniform -> s_load
                wa = u2h(wv.x); wb = u2h(wv.y);
            } else {
                wa = pkrtz(wr[dx], wr[dx + NO]);
                wb = pkrtz(wr[dx + 2 * NO], wr[dx + 3 * NO]);
            }
#pragma unroll
            for (int q = 0; q < 4; ++q) {
                const int m = dx + q;           // entry index in window, 0..11
                unsigned lo = (m & 1) ? E[m >> 1].z : E[m >> 1].x;
                unsigned hi = (m & 1) ? E[m >> 1].w : E[m >> 1].y;
                float s = FDOT2(wa * ha[q], u2h(lo), acc[q][dx]);
                acc[q][dx] = FDOT2(wb * hb[q], u2h(hi), s);
            }
        }
    }

    // out[b][g*81 + dy*9 + dx][h][w] for 4 px
    size_t obase = (((size_t)(pair * NO + dy * F_)) * H_ + (h0 + row_t)) * W_ + c0;
#pragma unroll
    for (int dx = 0; dx < F_; ++dx)
#pragma unroll
        for (int q = 0; q < 4; ++q)
            out[obase + (size_t)dx * HW_ + 2 * q] = acc[q][dx];
}

extern "C" void kernel_launch(void* const* d_in, const int* in_sizes, int n_in,
                              void* d_out, int out_size, void* d_ws, size_t ws_size,
                              hipStream_t stream) {
    const float* in1  = (const float*)d_in[0];
    const float* in2  = (const float*)d_in[1];
    const float* wraw = (const float*)d_in[2];
    float* out = (float*)d_out;

    const size_t wp_bytes = (size_t)G_ * NC4 * NO * 8;  // 41,472 B
    const int nblocks = 8 * 24 * F_;                    // 1728

    if (ws_size >= wp_bytes) {
        u32x2* wp = (u32x2*)d_ws;
        int n = G_ * NC4 * NO;
        pack_weights_kernel<<<(n + 255) / 256, 256, 0, stream>>>(wraw, wp);
        wcorr_kernel<true><<<nblocks, 256, 0, stream>>>(in1, in2, wp, wraw, out);
    } else {
        wcorr_kernel<false><<<nblocks, 256, 0, stream>>>(in1, in2, nullptr, wraw, out);
    }
}

// Round 10
// 76.824 us; speedup vs baseline: 3.4634x; 3.4634x over previous
//
#include <hip/hip_runtime.h>

// Problem constants (fixed by setup_inputs)
#define B_   4
#define C_   256
#define H_   96
#define W_   128
#define F_   9
#define G_   4
#define CG   64            // channels per group
#define NC4  16            // channel QUADS per group
#define NO   81            // offsets
#define TH   2             // output rows per block
#define TCOLS (W_ + 16)    // 144 cols incl halo
#define HW_  (H_ * W_)

// Per-pass geometry: 3 dy-values per pass (dy = pass*3 + dyp)
#define NDY   3
#define PROWS (2 * NDY)          // 6 tile rows per pass (dilation=2, TH=2)
#define PTE   (PROWS * TCOLS)    // 864 entries (8B: 4ch f16)
#define PNK   4                  // ceil(864/256) staging chunks

typedef _Float16 half2v __attribute__((ext_vector_type(2)));
typedef unsigned u32x2 __attribute__((ext_vector_type(2)));

__device__ __forceinline__ half2v u2h(unsigned u) {
    half2v h; __builtin_memcpy(&h, &u, 4); return h;
}
__device__ __forceinline__ unsigned h2u(half2v h) {
    unsigned u; __builtin_memcpy(&u, &h, 4); return u;
}
__device__ __forceinline__ half2v pkrtz(float a, float b) {
    auto r = __builtin_amdgcn_cvt_pkrtz(a, b);
    half2v h; __builtin_memcpy(&h, &r, 4); return h;
}
__device__ __forceinline__ unsigned pkrtz_u(float a, float b) {
    auto r = __builtin_amdgcn_cvt_pkrtz(a, b);
    unsigned u; __builtin_memcpy(&u, &r, 4); return u;
}

#if __has_builtin(__builtin_amdgcn_fdot2)
#define FDOT2(a, b, c) __builtin_amdgcn_fdot2((a), (b), (c), false)
#else
__device__ __forceinline__ float fdot2_fb(half2v a, half2v b, float c) {
    return c + (float)a[0] * (float)b[0] + (float)a[1] * (float)b[1];
}
#define FDOT2(a, b, c) fdot2_fb((a), (b), (c))
#endif

// Pack weights [C,9,9] f32 -> [g][c4][o] as 4-channel (2x f16x2) in d_ws
__global__ void pack_weights_kernel(const float* __restrict__ w,
                                    u32x2* __restrict__ wp) {
    int i = blockIdx.x * blockDim.x + threadIdx.x;
    if (i >= G_ * NC4 * NO) return;
    int o  = i % NO;
    int c4 = (i / NO) % NC4;
    int g  = i / (NO * NC4);
    const float* base = w + (size_t)(g * CG + 4 * c4) * NO + o;
    u32x2 r;
    r.x = pkrtz_u(base[0], base[NO]);
    r.y = pkrtz_u(base[2 * NO], base[3 * NO]);
    wp[i] = r;
}

template <bool PACKED>
__global__ __launch_bounds__(256)
void wcorr_kernel(const float* __restrict__ in1, const float* __restrict__ in2,
                  const u32x2* __restrict__ wp, const float* __restrict__ wraw,
                  float* __restrict__ out) {
    __shared__ u32x2 tile[2][PTE];   // 13,824 B (flat layout, R5-proven)

    // grid = 16 pairs x 3 passes x 48 hblks = 2304 blocks (9 blocks/CU)
    // XCD-aware: (b,g) pair constant per XCD run -> in2 plane stays in XCD L2
    int bid  = blockIdx.x;
    int xcd  = bid & 7;
    int slot = bid >> 3;                 // 0..287
    int pair = xcd + 8 * (slot / 144);   // 0..15  == b*4+g
    int rem  = slot % 144;
    int pass = rem / 48;                 // 0..2  (dy block)
    int hblk = rem % 48;
    int b = pair >> 2, g = pair & 3;
    int h0 = hblk * TH;

    int t  = threadIdx.x;
    int ty = t >> 7;                // 0..1
    int tx = t & 127;               // 0..127

    const float* in1g = in1 + (size_t)(b * C_ + g * CG) * HW_;
    const float* in2g = in2 + (size_t)(b * C_ + g * CG) * HW_;

    // ---- staging geometry (c4-invariant): clamp + mask, branchless ----
    const int gr0 = h0 - 8 + 6 * pass;
    int po[PNK]; unsigned msk[PNK];
#pragma unroll
    for (int k = 0; k < PNK; ++k) {
        int pidx = k * 256 + t;
        int row  = pidx / TCOLS;
        int hcol = pidx - row * TCOLS;
        int gr = gr0 + row, gc = hcol - 8;
        bool inb = (pidx < PTE) && gr >= 0 && gr < H_ && gc >= 0 && gc < W_;
        int off = gr * W_ + gc;
        off = off < 0 ? 0 : (off > HW_ - 1 ? HW_ - 1 : off);
        po[k]  = off;
        float m = inb ? 1.f : 0.f;
        msk[k] = pkrtz_u(m, m);
    }

    float acc[NDY * F_];
#pragma unroll
    for (int o = 0; o < NDY * F_; ++o) acc[o] = 0.f;

    // staged in2 values for ONE tile, live across a full compute phase
    float sv0[PNK], sv1[PNK], sv2[PNK], sv3[PNK];

    auto LOADS = [&](int c4n) {
        const float* chb = in2g + (size_t)(4 * c4n) * HW_;
#pragma unroll
        for (int k = 0; k < PNK; ++k) {
            const float* q = chb + po[k];
            sv0[k] = q[0];        sv1[k] = q[HW_];
            sv2[k] = q[2 * HW_];  sv3[k] = q[3 * HW_];
        }
    };
    auto WRITE = [&](u32x2* dst) {
#pragma unroll
        for (int k = 0; k < PNK; ++k) {
            if (k < PNK - 1 || t < PTE - (PNK - 1) * 256) {
                half2v m = u2h(msk[k]);
                u32x2 r;
                r.x = h2u(u2h(pkrtz_u(sv0[k], sv1[k])) * m);
                r.y = h2u(u2h(pkrtz_u(sv2[k], sv3[k])) * m);
                dst[k * 256 + t] = r;
            }
        }
    };

    // ---- prologue: tile 0 staged; tile 1 in flight ----
    LOADS(0);
    WRITE(tile[0]);
    LOADS(1);

    const int in1off = (h0 + ty) * W_ + tx;
    float a0 = in1g[in1off], a1 = in1g[in1off + HW_];
    float a2 = in1g[in1off + 2 * HW_], a3 = in1g[in1off + 3 * HW_];

    const int lbase = ty * TCOLS + tx;

    for (int c4 = 0; c4 < NC4; ++c4) {
        __syncthreads();   // tile[c4&1] readable; tile[(c4+1)&1] writable

        // write tile c4+1 (loads issued one FULL iteration ago -> vmcnt covered)
        if (c4 + 1 < NC4) WRITE(tile[(c4 + 1) & 1]);
        // issue loads for tile c4+2 (wait lands in NEXT iteration's WRITE)
        if (c4 + 2 < NC4) LOADS(c4 + 2);

        const u32x2* lt = tile[c4 & 1];
        half2v ha = pkrtz(a0, a1);
        half2v hb = pkrtz(a2, a3);
        if (c4 + 1 < NC4) {   // prefetch next in1 quad
            const float* pp = in1g + (size_t)(4 * (c4 + 1)) * HW_ + in1off;
            a0 = pp[0]; a1 = pp[HW_]; a2 = pp[2 * HW_]; a3 = pp[3 * HW_];
        }

        const u32x2* wrow = PACKED ? (wp + ((size_t)g * NC4 + c4) * NO + pass * NDY * F_) : nullptr;
        const float* wr = wraw + (size_t)(g * CG + 4 * c4) * NO + pass * NDY * F_;

#pragma unroll
        for (int dyp = 0; dyp < NDY; ++dyp) {
#pragma unroll
            for (int dx = 0; dx < F_; ++dx) {
                const int oo = dyp * F_ + dx;
                u32x2 uv = lt[lbase + dyp * 2 * TCOLS + dx * 2]; // ds_read_b64, imm offset
                half2v wa, wb;
                if (PACKED) {
                    u32x2 wv = wrow[oo];            // wave-uniform -> s_load
                    wa = u2h(wv.x); wb = u2h(wv.y);
                } else {
                    wa = pkrtz(wr[oo], wr[oo + NO]);
                    wb = pkrtz(wr[oo + 2 * NO], wr[oo + 3 * NO]);
                }
                half2v p0 = wa * ha;                // v_pk_mul_f16
                half2v p1 = wb * hb;
                float s = FDOT2(p0, u2h(uv.x), acc[oo]);
                acc[oo]  = FDOT2(p1, u2h(uv.y), s); // v_dot2_f32_f16 x2
            }
        }
    }

    // write this pass's 27 output planes: out[b][g*81 + pass*27 + oo][h][w]
    size_t obase = (((size_t)pair * NO + pass * NDY * F_) * H_ + (h0 + ty)) * W_ + tx;
#pragma unroll
    for (int oo = 0; oo < NDY * F_; ++oo)
        out[obase + (size_t)oo * HW_] = acc[oo];
}

extern "C" void kernel_launch(void* const* d_in, const int* in_sizes, int n_in,
                              void* d_out, int out_size, void* d_ws, size_t ws_size,
                              hipStream_t stream) {
    const float* in1  = (const float*)d_in[0];
    const float* in2  = (const float*)d_in[1];
    const float* wraw = (const float*)d_in[2];
    float* out = (float*)d_out;

    const size_t wp_bytes = (size_t)G_ * NC4 * NO * 8;  // 41,472 B
    const int nblocks = 16 * 3 * (H_ / TH);             // 2304

    if (ws_size >= wp_bytes) {
        u32x2* wp = (u32x2*)d_ws;
        int n = G_ * NC4 * NO;
        pack_weights_kernel<<<(n + 255) / 256, 256, 0, stream>>>(wraw, wp);
        wcorr_kernel<true><<<nblocks, 256, 0, stream>>>(in1, in2, wp, wraw, out);
    } else {
        wcorr_kernel<false><<<nblocks, 256, 0, stream>>>(in1, in2, nullptr, wraw, out);
    }
}

// Round 11
// 74.599 us; speedup vs baseline: 3.5668x; 1.0298x over previous
//
#include <hip/hip_runtime.h>

// Problem constants (fixed by setup_inputs)
#define B_   4
#define C_   256
#define H_   96
#define W_   128
#define F_   9
#define G_   4
#define CG   64            // channels per group
#define NC8  8             // channel OCTETS per group
#define NO   81            // offsets
#define HW_  (H_ * W_)

// Block: 4 output rows x 64 cols (half width); 3 dy per pass
#define NDY   3
#define TROWS 8                  // tap rows: r + 2*dyp, r=0..3, dyp=0..2 -> 0..7
#define TCOLS 80                 // 64 + 16 halo cols
#define PTE   (TROWS * TCOLS)    // 640 entries (16B: 8ch f16)
#define PNK   3                  // staging chunks 256+256+128

typedef _Float16 half2v __attribute__((ext_vector_type(2)));
typedef unsigned u32x4 __attribute__((ext_vector_type(4)));

__device__ __forceinline__ half2v u2h(unsigned u) {
    half2v h; __builtin_memcpy(&h, &u, 4); return h;
}
__device__ __forceinline__ unsigned h2u(half2v h) {
    unsigned u; __builtin_memcpy(&u, &h, 4); return u;
}
__device__ __forceinline__ half2v pkrtz(float a, float b) {
    auto r = __builtin_amdgcn_cvt_pkrtz(a, b);
    half2v h; __builtin_memcpy(&h, &r, 4); return h;
}
__device__ __forceinline__ unsigned pkrtz_u(float a, float b) {
    auto r = __builtin_amdgcn_cvt_pkrtz(a, b);
    unsigned u; __builtin_memcpy(&u, &r, 4); return u;
}

#if __has_builtin(__builtin_amdgcn_fdot2)
#define FDOT2(a, b, c) __builtin_amdgcn_fdot2((a), (b), (c), false)
#else
__device__ __forceinline__ float fdot2_fb(half2v a, half2v b, float c) {
    return c + (float)a[0] * (float)b[0] + (float)a[1] * (float)b[1];
}
#define FDOT2(a, b, c) fdot2_fb((a), (b), (c))
#endif

// Pack weights [C,9,9] f32 -> [g][c8][o] as 8-channel (4x f16x2) in d_ws
__global__ void pack_weights_kernel(const float* __restrict__ w,
                                    u32x4* __restrict__ wp) {
    int i = blockIdx.x * blockDim.x + threadIdx.x;
    if (i >= G_ * NC8 * NO) return;
    int o  = i % NO;
    int c8 = (i / NO) % NC8;
    int g  = i / (NO * NC8);
    const float* base = w + (size_t)(g * CG + 8 * c8) * NO + o;
    u32x4 r;
    r.x = pkrtz_u(base[0 * NO], base[1 * NO]);
    r.y = pkrtz_u(base[2 * NO], base[3 * NO]);
    r.z = pkrtz_u(base[4 * NO], base[5 * NO]);
    r.w = pkrtz_u(base[6 * NO], base[7 * NO]);
    wp[i] = r;
}

template <bool PACKED>
__global__ __launch_bounds__(256)
void wcorr_kernel(const float* __restrict__ in1, const float* __restrict__ in2,
                  const u32x4* __restrict__ wp, const float* __restrict__ wraw,
                  float* __restrict__ out) {
    __shared__ u32x4 tile[2][PTE];   // 20,480 B

    // grid = 2304: 16 pairs x {3 pass x 24 hblk x 2 half}
    // XCD-aware: (b,g) pair constant per XCD run -> in2 plane stays in XCD L2
    int bid  = blockIdx.x;
    int xcd  = bid & 7;
    int slot = bid >> 3;                 // 0..287
    int pair = xcd + 8 * (slot / 144);   // 0..15  == b*4+g
    int rem  = slot % 144;
    int pass = rem / 48;                 // 0..2  (dy block)
    int sub  = rem % 48;
    int hblk = sub >> 1;                 // 0..23
    int half = sub & 1;                  // col half
    int b = pair >> 2, g = pair & 3;
    int h0 = hblk * 4;
    int w0 = half * 64;

    int t = threadIdx.x;
    int r = t >> 6;                 // 0..3 output row (uniform per wave)
    int x = t & 63;                 // 0..63 output col within half

    const float* in1g = in1 + (size_t)(b * C_ + g * CG) * HW_;
    const float* in2g = in2 + (size_t)(b * C_ + g * CG) * HW_;

    // ---- staging geometry (c8-invariant): clamp + mask, branchless ----
    const int gr0 = h0 - 8 + 6 * pass;
    const int gc0 = w0 - 8;
    int po[PNK]; unsigned msk[PNK];
#pragma unroll
    for (int k = 0; k < PNK; ++k) {
        int pidx = k * 256 + t;
        int row  = pidx / TCOLS;
        int col  = pidx - row * TCOLS;
        int gr = gr0 + row, gc = gc0 + col;
        bool inb = (pidx < PTE) && gr >= 0 && gr < H_ && gc >= 0 && gc < W_;
        int off = gr * W_ + gc;
        off = off < 0 ? 0 : (off > HW_ - 1 ? HW_ - 1 : off);
        po[k]  = off;
        float m = inb ? 1.f : 0.f;
        msk[k] = pkrtz_u(m, m);
    }

    float acc[NDY * F_];
#pragma unroll
    for (int o = 0; o < NDY * F_; ++o) acc[o] = 0.f;

    // staged in2 values for ONE tile (8 ch x PNK chunks), live across compute
    float sv[PNK][8];

    auto LOADS = [&](int c8n) {
        const float* chb = in2g + (size_t)(8 * c8n) * HW_;
#pragma unroll
        for (int k = 0; k < PNK; ++k) {
            const float* q = chb + po[k];
#pragma unroll
            for (int j = 0; j < 8; ++j) sv[k][j] = q[(size_t)j * HW_];
        }
    };
    auto WRITE = [&](u32x4* dst) {
#pragma unroll
        for (int k = 0; k < PNK; ++k) {
            if (k < PNK - 1 || t < PTE - (PNK - 1) * 256) {
                half2v m = u2h(msk[k]);
                u32x4 e;
                e.x = h2u(u2h(pkrtz_u(sv[k][0], sv[k][1])) * m);
                e.y = h2u(u2h(pkrtz_u(sv[k][2], sv[k][3])) * m);
                e.z = h2u(u2h(pkrtz_u(sv[k][4], sv[k][5])) * m);
                e.w = h2u(u2h(pkrtz_u(sv[k][6], sv[k][7])) * m);
                dst[k * 256 + t] = e;    // ds_write_b128, contiguous
            }
        }
    };

    // ---- prologue: tile 0 staged; tile 1 in flight ----
    LOADS(0);
    WRITE(tile[0]);
    LOADS(1);

    const int in1off = (h0 + r) * W_ + (w0 + x);
    float a[8];
#pragma unroll
    for (int j = 0; j < 8; ++j) a[j] = in1g[in1off + (size_t)j * HW_];

    for (int c8 = 0; c8 < NC8; ++c8) {
        __syncthreads();   // tile[c8&1] readable; tile[(c8+1)&1] writable

        // write tile c8+1 (loads issued one FULL iteration ago -> vmcnt covered)
        if (c8 + 1 < NC8) WRITE(tile[(c8 + 1) & 1]);
        // issue loads for tile c8+2 (wait lands in NEXT iteration's WRITE)
        if (c8 + 2 < NC8) LOADS(c8 + 2);

        // pack current in1, then prefetch next octet into the same floats
        half2v ha0 = pkrtz(a[0], a[1]), ha1 = pkrtz(a[2], a[3]);
        half2v ha2 = pkrtz(a[4], a[5]), ha3 = pkrtz(a[6], a[7]);
        if (c8 + 1 < NC8) {
            const float* pp = in1g + (size_t)(8 * (c8 + 1)) * HW_ + in1off;
#pragma unroll
            for (int j = 0; j < 8; ++j) a[j] = pp[(size_t)j * HW_];
        }

        const u32x4* lt = tile[c8 & 1];
        const u32x4* wrow = PACKED ? (wp + ((size_t)g * NC8 + c8) * NO + pass * NDY * F_) : nullptr;
        const float* wr = wraw + (size_t)(g * CG + 8 * c8) * NO + pass * NDY * F_;

#pragma unroll
        for (int dyp = 0; dyp < NDY; ++dyp) {
            const u32x4* rowp = lt + (r + 2 * dyp) * TCOLS + x;
#pragma unroll
            for (int dx = 0; dx < F_; ++dx) {
                const int oo = dyp * F_ + dx;
                u32x4 uv = rowp[2 * dx];            // ds_read_b128, imm offset
                half2v w0h, w1h, w2h, w3h;
                if (PACKED) {
                    u32x4 wv = wrow[oo];            // block-uniform -> s_load x4
                    w0h = u2h(wv.x); w1h = u2h(wv.y);
                    w2h = u2h(wv.z); w3h = u2h(wv.w);
                } else {
                    w0h = pkrtz(wr[oo + 0 * NO], wr[oo + 1 * NO]);
                    w1h = pkrtz(wr[oo + 2 * NO], wr[oo + 3 * NO]);
                    w2h = pkrtz(wr[oo + 4 * NO], wr[oo + 5 * NO]);
                    w3h = pkrtz(wr[oo + 6 * NO], wr[oo + 7 * NO]);
                }
                float s = acc[oo];
                s = FDOT2(w0h * ha0, u2h(uv.x), s);
                s = FDOT2(w1h * ha1, u2h(uv.y), s);
                s = FDOT2(w2h * ha2, u2h(uv.z), s);
                s = FDOT2(w3h * ha3, u2h(uv.w), s);
                acc[oo] = s;
            }
        }
    }

    // out[b][g*81 + pass*27 + oo][h][w]
    size_t obase = (((size_t)pair * NO + pass * NDY * F_) * H_ + (h0 + r)) * W_ + (w0 + x);
#pragma unroll
    for (int oo = 0; oo < NDY * F_; ++oo)
        out[obase + (size_t)oo * HW_] = acc[oo];
}

extern "C" void kernel_launch(void* const* d_in, const int* in_sizes, int n_in,
                              void* d_out, int out_size, void* d_ws, size_t ws_size,
                              hipStream_t stream) {
    const float* in1  = (const float*)d_in[0];
    const float* in2  = (const float*)d_in[1];
    const float* wraw = (const float*)d_in[2];
    float* out = (float*)d_out;

    const size_t wp_bytes = (size_t)G_ * NC8 * NO * 16;  // 41,472 B
    const int nblocks = 16 * 144;                        // 2304

    if (ws_size >= wp_bytes) {
        u32x4* wp = (u32x4*)d_ws;
        int n = G_ * NC8 * NO;
        pack_weights_kernel<<<(n + 255) / 256, 256, 0, stream>>>(wraw, wp);
        wcorr_kernel<true><<<nblocks, 256, 0, stream>>>(in1, in2, wp, wraw, out);
    } else {
        wcorr_kernel<false><<<nblocks, 256, 0, stream>>>(in1, in2, nullptr, wraw, out);
    }
}